// Round 6
// baseline (225.183 us; speedup 1.0000x reference)
//
#include <hip/hip_runtime.h>
#include <hip/hip_fp16.h>

#define N_NODES 100000
#define N_EDGES 3200000
#define E_TOT   (N_EDGES + N_NODES)   // 3.3M edges incl self-loops
#define IN_C 128
#define HID  16
#define OUTC 5
#define NEG_SLOPE 0.2f

#define NBKT 391        // buckets of 256 dsts: b = dst >> 8
#define CAP  9216       // per-bucket capacity (mean 8440, +8.5 sigma)
#define P_TILE 4096     // smaller tile -> 27.7KB partition LDS -> 5 blocks/CU
#define PART_GRID ((E_TOT + P_TILE - 1) / P_TILE)   // 806
#define NT 64                                        // nodes per projection tile
#define PROJ_GRID ((N_NODES + NT - 1) / NT)          // 1563
#define AGG_GRID ((N_NODES + 15) / 16)               // 6250 (gat1/gat2 grids)
#define XH 136          // sXh row stride in halves: 272B = 16B-aligned rows, 2-way bank alias (free)
#define XPADW 132       // sWt row stride in floats: 528B, 16B-aligned, 2-way alias

__device__ __forceinline__ float pk_half2(float a, float b) {
    __half2 h = __halves2half2(__float2half(a), __float2half(b));
    return *(float*)&h;
}
__device__ __forceinline__ float2 unpk_half2(float v) {
    return __half22float2(*(__half2*)&v);
}

// ============ fused: edge partition (blocks 0..805) + layer-1 projection ============
__global__ __launch_bounds__(256) void partproj_k(
    const int* __restrict__ ei, int* __restrict__ gcnt, unsigned* __restrict__ pairs,
    const float* __restrict__ x, const float* __restrict__ W1,
    const float* __restrict__ att_d,
    __half* __restrict__ h1f, float* __restrict__ a_dst) {
    __shared__ __align__(16) char smem[27712];
    int t = threadIdx.x;
    if (blockIdx.x < PART_GRID) {
        // ---- partition path: staged vbuf/bbuf form (L2 write-combining on pairs) ----
        unsigned* vbuf       = (unsigned*)smem;                  // 16384 B
        unsigned short* bbuf = (unsigned short*)(smem + 16384);  //  8192 B
        int* hist            = (int*)(smem + 24576);             //  1564 B
        int* cur             = (int*)(smem + 26140);             //  1564 B
        for (int i = t; i < NBKT; i += 256) hist[i] = 0;
        __syncthreads();
        int base = blockIdx.x * P_TILE;
        int lim = E_TOT - base; if (lim > P_TILE) lim = P_TILE;
        for (int i = t; i < lim; i += 256) {
            int e = base + i;
            int s, d;
            if (e < N_EDGES) { s = ei[e]; d = ei[N_EDGES + e]; }
            else             { s = e - N_EDGES; d = s; }
            int b = d >> 8;
            vbuf[i] = ((unsigned)s << 8) | (unsigned)(d & 255);
            bbuf[i] = (unsigned short)b;
            atomicAdd(&hist[b], 1);
        }
        __syncthreads();
        for (int i = t; i < NBKT; i += 256) {
            int h = hist[i];
            cur[i] = h ? atomicAdd(&gcnt[i], h) : 0;   // reserve [cur, cur+h)
        }
        __syncthreads();
        for (int i = t; i < lim; i += 256) {
            int b = bbuf[i];
            int p = atomicAdd(&cur[b], 1);
            if (p >= 0 && p < CAP) pairs[(size_t)b * CAP + p] = vbuf[i];
        }
    } else {
        // ---------- projection path: h1 = x@W1, 2x2 register tile, fp16 x-tile ----------
        // sXh: 64 x 136 halves = 17408 B ; sWt: 16 x 132 floats = 8448 B  (total 25856)
        __half* sXh = (__half*)smem;
        float*  sWt = (float*)(smem + 17408);
        int bid = blockIdx.x - PART_GRID;
        int node0 = bid * NT;
        // stage W transposed: sWt[c*XPADW + k] = W1[k*16 + c]
        for (int i = t; i < IN_C * HID; i += 256) {
            int k = i >> 4, c = i & 15;
            sWt[c * XPADW + k] = W1[i];
        }
        // stage x tile as fp16 (8B per float4 source)
        const float4* x4 = (const float4*)x;
        for (int i = t; i < NT * 32; i += 256) {     // 2048 float4
            int r = i >> 5, c4 = i & 31;
            int node = node0 + r;
            float4 v = make_float4(0.f, 0.f, 0.f, 0.f);
            if (node < N_NODES) v = x4[(size_t)node * 32 + c4];
            __half2 h01 = __halves2half2(__float2half(v.x), __float2half(v.y));
            __half2 h23 = __halves2half2(__float2half(v.z), __float2half(v.w));
            float2 pk;
            pk.x = *(float*)&h01;
            pk.y = *(float*)&h23;
            *(float2*)&sXh[r * XH + c4 * 4] = pk;    // byte off 272r+8c4: 8-aligned
        }
        __syncthreads();
        int rp = t >> 3, cp = t & 7;                 // 32 row-pairs x 8 col-pairs
        const __half* xr0 = &sXh[(2 * rp)     * XH];
        const __half* xr1 = &sXh[(2 * rp + 1) * XH];
        const float*  wr0 = &sWt[(2 * cp)     * XPADW];
        const float*  wr1 = &sWt[(2 * cp + 1) * XPADW];
        float4 A00 = make_float4(0.f, 0.f, 0.f, 0.f);
        float4 A01 = A00, A10 = A00, A11 = A00;
        #pragma unroll 4
        for (int kk = 0; kk < 16; ++kk) {            // 8 k's per iteration
            float4 hx0 = *(const float4*)&xr0[kk * 8];   // 8 halves, row 2rp
            float4 hx1 = *(const float4*)&xr1[kk * 8];   // 8 halves, row 2rp+1
            float4 w0a = *(const float4*)&wr0[kk * 8];
            float4 w0b = *(const float4*)&wr0[kk * 8 + 4];
            float4 w1a = *(const float4*)&wr1[kk * 8];
            float4 w1b = *(const float4*)&wr1[kk * 8 + 4];
            float2 x00 = unpk_half2(hx0.x), x01 = unpk_half2(hx0.y);
            float2 x02 = unpk_half2(hx0.z), x03 = unpk_half2(hx0.w);
            float2 x10 = unpk_half2(hx1.x), x11 = unpk_half2(hx1.y);
            float2 x12 = unpk_half2(hx1.z), x13 = unpk_half2(hx1.w);
            A00.x += x00.x * w0a.x; A00.y += x00.y * w0a.y;
            A00.z += x01.x * w0a.z; A00.w += x01.y * w0a.w;
            A00.x += x02.x * w0b.x; A00.y += x02.y * w0b.y;
            A00.z += x03.x * w0b.z; A00.w += x03.y * w0b.w;
            A01.x += x00.x * w1a.x; A01.y += x00.y * w1a.y;
            A01.z += x01.x * w1a.z; A01.w += x01.y * w1a.w;
            A01.x += x02.x * w1b.x; A01.y += x02.y * w1b.y;
            A01.z += x03.x * w1b.z; A01.w += x03.y * w1b.w;
            A10.x += x10.x * w0a.x; A10.y += x10.y * w0a.y;
            A10.z += x11.x * w0a.z; A10.w += x11.y * w0a.w;
            A10.x += x12.x * w0b.x; A10.y += x12.y * w0b.y;
            A10.z += x13.x * w0b.z; A10.w += x13.y * w0b.w;
            A11.x += x10.x * w1a.x; A11.y += x10.y * w1a.y;
            A11.z += x11.x * w1a.z; A11.w += x11.y * w1a.w;
            A11.x += x12.x * w1b.x; A11.y += x12.y * w1b.y;
            A11.z += x13.x * w1b.z; A11.w += x13.y * w1b.w;
        }
        float h00 = A00.x + A00.y + A00.z + A00.w;   // node 2rp,   col 2cp
        float h01 = A01.x + A01.y + A01.z + A01.w;   // node 2rp,   col 2cp+1
        float h10 = A10.x + A10.y + A10.z + A10.w;   // node 2rp+1, col 2cp
        float h11 = A11.x + A11.y + A11.z + A11.w;   // node 2rp+1, col 2cp+1
        // a_dst partials + 8-lane shuffle reduce (lane groups of 8 are xor-closed)
        float ad0 = att_d[2 * cp], ad1 = att_d[2 * cp + 1];
        float pd0 = h00 * ad0 + h01 * ad1;
        float pd1 = h10 * ad0 + h11 * ad1;
        #pragma unroll
        for (int off = 1; off < 8; off <<= 1) {
            pd0 += __shfl_xor(pd0, off);
            pd1 += __shfl_xor(pd1, off);
        }
        int n0 = node0 + 2 * rp, n1 = n0 + 1;
        __half2* hp = (__half2*)h1f;
        if (n0 < N_NODES) {
            hp[(size_t)n0 * 8 + cp] = __halves2half2(__float2half(h00), __float2half(h01));
            if (cp == 0) a_dst[n0] = pd0;
        }
        if (n1 < N_NODES) {
            hp[(size_t)n1 * 8 + cp] = __halves2half2(__float2half(h10), __float2half(h11));
            if (cp == 0) a_dst[n1] = pd1;
        }
    }
}

// ======== CSR build: ONE 512-thread block per bucket, 256 counters, single pass ====
__global__ __launch_bounds__(512) void build_k(const unsigned* __restrict__ pairs,
                                               const int* __restrict__ gcnt,
                                               int* __restrict__ csr,
                                               int2* __restrict__ rs_cnt) {
    __shared__ int ccnt[256], sexc[256], cur[256];
    int t = threadIdx.x;
    int parent = blockIdx.x;
    if (t < 256) ccnt[t] = 0;
    __syncthreads();
    int tot = gcnt[parent];
    if (tot > CAP) tot = CAP; if (tot < 0) tot = 0;
    size_t pb = (size_t)parent * CAP;
    for (int i = t; i < tot; i += 512) {
        unsigned v = pairs[pb + i];
        atomicAdd(&ccnt[v & 255u], 1);
    }
    __syncthreads();
    if (t < 256) sexc[t] = ccnt[t];
    __syncthreads();
    for (int off = 1; off < 256; off <<= 1) {
        int xv = 0;
        if (t < 256 && t >= off) xv = sexc[t - off];
        __syncthreads();
        if (t < 256) sexc[t] += xv;
        __syncthreads();
    }
    int gbase = (int)pb;
    int regend = gbase + CAP;
    if (t < 256) {
        int excl = sexc[t] - ccnt[t];
        cur[t] = gbase + excl;
        int node = (parent << 8) + t;
        if (node < N_NODES) {
            int c = ccnt[t];
            if (excl + c > CAP) c = (excl < CAP) ? (CAP - excl) : 0;
            rs_cnt[node] = make_int2(gbase + excl, c);
        }
    }
    __syncthreads();
    for (int i = t; i < tot; i += 512) {
        unsigned v = pairs[pb + i];
        int pos = atomicAdd(&cur[v & 255u], 1);
        if (pos < regend) csr[pos] = (int)(v >> 8);
    }
}

// ===== layer-1 aggregate: pair-split channels (lane pair shares an edge; each lane
// loads ONE float4 = half the h1 row). acc[8]; 7-shuffle butterfly reduce.
__global__ __launch_bounds__(256) void gat1_k(
    const int* __restrict__ csr, const int2* __restrict__ rs_cnt,
    const __half* __restrict__ h1f, const float* __restrict__ att_s1,
    const float* __restrict__ adst1, const float* __restrict__ b1,
    const float* __restrict__ W2, const float* __restrict__ as2,
    const float* __restrict__ ad2, float4* __restrict__ h2p,
    float* __restrict__ adst2) {
    __shared__ float sW2t[OUTC][20];   // W2 transposed, rows padded to 20 floats
    __shared__ float sG[16][16];       // per-local-node g values
    __shared__ float sH2[16][8];       // per-local-node h2 staging
    __shared__ float sAsd[16];         // [0..4]=as2, [8..12]=ad2
    int t = threadIdx.x;
    if (t < 16) sAsd[t] = 0.0f;
    if (t < HID * OUTC) sW2t[t % OUTC][t / OUTC] = W2[t];
    if (t < OUTC) { sAsd[t] = as2[t]; sAsd[8 + t] = ad2[t]; }
    int lane  = t & 15;
    int sub   = lane & 1;        // which half of the channel vector this lane owns
    int eslot = lane >> 1;       // 8 edge slots per node
    int ch = sub * 8 + ((lane >> 1) & 1) * 4 + ((lane >> 2) & 1) * 2 + ((lane >> 3) & 1);
    float rB1 = b1[ch];
    float attr[8];
    #pragma unroll
    for (int j = 0; j < 8; ++j) attr[j] = att_s1[sub * 8 + j];
    __syncthreads();

    int node = (blockIdx.x * 256 + t) >> 4;   // grid exact: 6250*256/16 = 100000
    int2 rc = rs_cnt[node];
    int start = rc.x, len = rc.y;
    float ad  = adst1[node];

    float acc[8];
    #pragma unroll
    for (int c = 0; c < 8; ++c) acc[c] = 0.0f;
    float accd = 0.0f;
    int it = eslot;
    for (; it + 8 < len; it += 16) {
        int s0 = csr[start + it];
        int s1 = csr[start + it + 8];
        float4 p = *(const float4*)(h1f + (size_t)s0 * HID + sub * 8);
        float4 q = *(const float4*)(h1f + (size_t)s1 * HID + sub * 8);
        float2 f0 = unpk_half2(p.x), f1 = unpk_half2(p.y);
        float2 f2 = unpk_half2(p.z), f3 = unpk_half2(p.w);
        float2 g0 = unpk_half2(q.x), g1 = unpk_half2(q.y);
        float2 g2 = unpk_half2(q.z), g3 = unpk_half2(q.w);
        float pp0 = f0.x*attr[0] + f0.y*attr[1] + f1.x*attr[2] + f1.y*attr[3]
                  + f2.x*attr[4] + f2.y*attr[5] + f3.x*attr[6] + f3.y*attr[7];
        float pp1 = g0.x*attr[0] + g0.y*attr[1] + g1.x*attr[2] + g1.y*attr[3]
                  + g2.x*attr[4] + g2.y*attr[5] + g3.x*attr[6] + g3.y*attr[7];
        float v0 = pp0 + __shfl_xor(pp0, 1) + ad;   // pair-sum -> full att_src dot
        float v1 = pp1 + __shfl_xor(pp1, 1) + ad;
        v0 = (v0 > 0.0f) ? v0 : NEG_SLOPE * v0;
        v1 = (v1 > 0.0f) ? v1 : NEG_SLOPE * v1;
        float e0 = __expf(v0), e1 = __expf(v1);
        accd += e0 + e1;
        acc[0] += e0 * f0.x + e1 * g0.x; acc[1] += e0 * f0.y + e1 * g0.y;
        acc[2] += e0 * f1.x + e1 * g1.x; acc[3] += e0 * f1.y + e1 * g1.y;
        acc[4] += e0 * f2.x + e1 * g2.x; acc[5] += e0 * f2.y + e1 * g2.y;
        acc[6] += e0 * f3.x + e1 * g3.x; acc[7] += e0 * f3.y + e1 * g3.y;
    }
    if (it < len) {
        int s = csr[start + it];
        float4 p = *(const float4*)(h1f + (size_t)s * HID + sub * 8);
        float2 f0 = unpk_half2(p.x), f1 = unpk_half2(p.y);
        float2 f2 = unpk_half2(p.z), f3 = unpk_half2(p.w);
        float pp = f0.x*attr[0] + f0.y*attr[1] + f1.x*attr[2] + f1.y*attr[3]
                 + f2.x*attr[4] + f2.y*attr[5] + f3.x*attr[6] + f3.y*attr[7];
        float v = pp + __shfl_xor(pp, 1) + ad;
        v = (v > 0.0f) ? v : NEG_SLOPE * v;
        float ex = __expf(v);
        accd += ex;
        acc[0] += ex * f0.x; acc[1] += ex * f0.y;
        acc[2] += ex * f1.x; acc[3] += ex * f1.y;
        acc[4] += ex * f2.x; acc[5] += ex * f2.y;
        acc[6] += ex * f3.x; acc[7] += ex * f3.y;
    }
    // ---- halving butterfly across the 8 edge-slots (xor 2,4,8): 7 shuffles ----
    {
        bool b2 = (lane & 2) != 0;
        #pragma unroll
        for (int c = 0; c < 4; ++c) {
            float send = b2 ? acc[c] : acc[c + 4];
            float r = __shfl_xor(send, 2);
            acc[c] = (b2 ? acc[c + 4] : acc[c]) + r;
        }
        bool b4 = (lane & 4) != 0;
        #pragma unroll
        for (int c = 0; c < 2; ++c) {
            float send = b4 ? acc[c] : acc[c + 2];
            float r = __shfl_xor(send, 4);
            acc[c] = (b4 ? acc[c + 2] : acc[c]) + r;
        }
        bool b8 = (lane & 8) != 0;
        {
            float send = b8 ? acc[0] : acc[1];
            float r = __shfl_xor(send, 8);
            acc[0] = (b8 ? acc[1] : acc[0]) + r;
        }
    }
    accd += __shfl_xor(accd, 2);
    accd += __shfl_xor(accd, 4);
    accd += __shfl_xor(accd, 8);

    float inv = 1.0f / (accd + 1e-16f);
    float g = fmaxf(acc[0] * inv + rB1, 0.0f);   // lane holds channel ch
    int nl = t >> 4;
    sG[nl][ch] = g;                 // wave-local: written & read by the same wave
    if (lane < OUTC) {
        const float4* gp = (const float4*)sG[nl];
        const float4* wp = (const float4*)sW2t[lane];
        float h2v = 0.0f;
        #pragma unroll
        for (int k4 = 0; k4 < 4; ++k4) {
            float4 gv = gp[k4], wv = wp[k4];
            h2v += gv.x * wv.x + gv.y * wv.y + gv.z * wv.z + gv.w * wv.w;
        }
        sH2[nl][lane] = h2v;
        if (lane == 0) {
            float4 hv = *(const float4*)&sH2[nl][0];
            float h24 = sH2[nl][4];
            float4 as4 = *(const float4*)&sAsd[0]; float as_4 = sAsd[4];
            float4 ad4 = *(const float4*)&sAsd[8]; float ad_4 = sAsd[12];
            float s2 = hv.x * as4.x + hv.y * as4.y + hv.z * as4.z + hv.w * as4.w + h24 * as_4;
            float d2 = hv.x * ad4.x + hv.y * ad4.y + hv.z * ad4.z + hv.w * ad4.w + h24 * ad_4;
            adst2[node] = d2;
            float4 r;
            r.x = s2;
            r.y = pk_half2(hv.x, hv.y);
            r.z = pk_half2(hv.z, hv.w);
            r.w = pk_half2(h24, 0.0f);
            h2p[node] = r;
        }
    }
}

// ===== layer-2 aggregate (16 lanes/node, unroll-2) + bias + log_softmax -> out =====
__global__ __launch_bounds__(256) void gat2_k(
    const int* __restrict__ csr, const int2* __restrict__ rs_cnt,
    const float4* __restrict__ h2p, const float* __restrict__ adst2,
    const float* __restrict__ b2, float* __restrict__ out) {
    __shared__ float sB2[OUTC];
    int t = threadIdx.x;
    if (t < OUTC) sB2[t] = b2[t];
    __syncthreads();

    int node = (blockIdx.x * 256 + t) >> 4;
    int lane = t & 15;
    int2 rc = rs_cnt[node];
    int start = rc.x, len = rc.y;
    float ad  = adst2[node];

    float acc[OUTC];
    #pragma unroll
    for (int c = 0; c < OUTC; ++c) acc[c] = 0.0f;
    float accd = 0.0f;
    int it = lane;
    for (; it + 16 < len; it += 32) {
        int s0 = csr[start + it];
        int s1 = csr[start + it + 16];
        float4 r0 = h2p[s0];
        float4 r1 = h2p[s1];
        float v0 = r0.x + ad;
        float v1 = r1.x + ad;
        v0 = (v0 > 0.0f) ? v0 : NEG_SLOPE * v0;
        v1 = (v1 > 0.0f) ? v1 : NEG_SLOPE * v1;
        float e0 = __expf(v0), e1 = __expf(v1);
        accd += e0 + e1;
        float2 a01 = unpk_half2(r0.y), a23 = unpk_half2(r0.z), a4 = unpk_half2(r0.w);
        float2 b01 = unpk_half2(r1.y), b23 = unpk_half2(r1.z), b4 = unpk_half2(r1.w);
        acc[0] += e0 * a01.x + e1 * b01.x;
        acc[1] += e0 * a01.y + e1 * b01.y;
        acc[2] += e0 * a23.x + e1 * b23.x;
        acc[3] += e0 * a23.y + e1 * b23.y;
        acc[4] += e0 * a4.x  + e1 * b4.x;
    }
    if (it < len) {
        int s = csr[start + it];
        float4 r = h2p[s];
        float v = r.x + ad;
        v = (v > 0.0f) ? v : NEG_SLOPE * v;
        float ex = __expf(v);
        accd += ex;
        float2 f01 = unpk_half2(r.y), f23 = unpk_half2(r.z), f4 = unpk_half2(r.w);
        acc[0] += ex * f01.x; acc[1] += ex * f01.y;
        acc[2] += ex * f23.x; acc[3] += ex * f23.y;
        acc[4] += ex * f4.x;
    }
    #pragma unroll
    for (int off = 8; off; off >>= 1) {
        accd += __shfl_xor(accd, off);
        #pragma unroll
        for (int c = 0; c < OUTC; ++c) acc[c] += __shfl_xor(acc[c], off);
    }
    if (lane == 0) {
        float inv = 1.0f / (accd + 1e-16f);
        float val[OUTC];
        float mx = -3.4e38f;
        #pragma unroll
        for (int c = 0; c < OUTC; ++c) {
            val[c] = acc[c] * inv + sB2[c];
            mx = fmaxf(mx, val[c]);
        }
        float se = 0.0f;
        #pragma unroll
        for (int c = 0; c < OUTC; ++c) se += __expf(val[c] - mx);
        float lse = logf(se) + mx;
        #pragma unroll
        for (int c = 0; c < OUTC; ++c)
            out[(size_t)node * OUTC + c] = val[c] - lse;
    }
}

extern "C" void kernel_launch(void* const* d_in, const int* in_sizes, int n_in,
                              void* d_out, int out_size, void* d_ws, size_t ws_size,
                              hipStream_t stream) {
    const float* x    = (const float*)d_in[0];
    const int*   ei   = (const int*)d_in[1];
    const float* W1   = (const float*)d_in[2];
    const float* as1  = (const float*)d_in[3];
    const float* ad1  = (const float*)d_in[4];
    const float* b1   = (const float*)d_in[5];
    const float* W2   = (const float*)d_in[6];
    const float* as2  = (const float*)d_in[7];
    const float* ad2  = (const float*)d_in[8];
    const float* b2   = (const float*)d_in[9];
    float* out = (float*)d_out;

    char* wsb = (char*)d_ws;
    unsigned* pairs = (unsigned*)wsb;
    float4* h2p     = (float4*)wsb;                       // alias (post-build)
    float*  adst2   = (float*)(wsb + 1600000);            // alias (post-build)
    int*    csr     = (int*)(wsb + 14413824);
    __half* h1f     = (__half*)(wsb + 28827648);
    float*  adst1   = (float*)(wsb + 32427648);
    int2*   rs_cnt  = (int2*)(wsb + 32827648);
    int*    gcnt    = (int*)(wsb + 33627648);

    // ---- zero bucket totals ----
    hipMemsetAsync(gcnt, 0, NBKT * sizeof(int), stream);
    // ---- fused: edge partition (806 blocks) + layer-1 projection (1563 64-node tiles) ----
    partproj_k<<<PART_GRID + PROJ_GRID, 256, 0, stream>>>(
        ei, gcnt, pairs, x, W1, ad1, h1f, adst1);
    // ---- CSR build (391 one-per-bucket 512-thread blocks, single pass) ----
    build_k<<<NBKT, 512, 0, stream>>>(pairs, gcnt, csr, rs_cnt);
    // ---- layer 1 aggregate + relu + layer-2 projection (fused) ----
    gat1_k<<<AGG_GRID, 256, 0, stream>>>(csr, rs_cnt, h1f, as1, adst1, b1,
                                         W2, as2, ad2, h2p, adst2);
    // ---- layer 2 aggregate + log_softmax ----
    gat2_k<<<AGG_GRID, 256, 0, stream>>>(csr, rs_cnt, h2p, adst2, b2, out);
}